// Round 2
// baseline (17452.495 us; speedup 1.0000x reference)
//
#include <hip/hip_runtime.h>
#include <cstdint>
#include <cstddef>

// ---------------------------------------------------------------------------
// Residual VQ (SoundStream Alg.1) on MI355X — R2.
// R1 post-mortem: 132KB LDS -> 1 block/CU -> 1 wave/SIMD -> barrier drains
// exposed (VALUBusy 45%). R2: MPTS 32->16, KC 8->4 => ~67KB LDS => 2 blocks/CU
// (2 waves/SIMD). Waves split codes 2-way x points 2-way (8pts x 512codes,
// 1.0 B-LDS/FMA, parity with VALU pipe). Argmin merges the two code-halves
// via LDS; exact fp64 refinement of near-ties unchanged (indices = exact
// arithmetic argmin). Losses in fp64 via global atomics.
// ---------------------------------------------------------------------------

#define BATCH 8
#define SEQ   2048
#define DIM   512
#define NUMQ  8
#define CODES 1024
#define NPTS  (BATCH*SEQ)            // 16384
#define MPTS  16                     // points per workgroup
#define NWG   (NPTS/MPTS)            // 1024
#define NTHR  256
#define KC    4                      // k-chunk depth staged per buffer
#define NKC   (DIM/KC)               // 128

#define OUT_IDX   (BATCH*SEQ*DIM)             // 8388608
#define OUT_LOSS  (OUT_IDX + BATCH*SEQ*NUMQ)  // 8519680

#define WS_LOSS    0                          // 8 doubles
#define WS_CNORM   1024                       // 8192 floats
#define WS_CBT     40960                      // 8*512*1024 floats (k-major)
#define WS_NEED_T  (WS_CBT + (size_t)NUMQ*DIM*CODES*4)

__global__ void k_zero(double* loss) {
  if (threadIdx.x < NUMQ) loss[threadIdx.x] = 0.0;
}

// per-code squared norm (fp32; only feeds the approximate fp32 scores)
__global__ void k_cnorm(const float* __restrict__ cb, float* __restrict__ cnorm) {
  int r = blockIdx.x * blockDim.x + threadIdx.x;      // 0..8191
  const float* row = cb + (size_t)r * DIM;
  float s = 0.f;
  for (int d = 0; d < DIM; d += 4) {
    float4 v = *(const float4*)(row + d);
    s += v.x * v.x + v.y * v.y + v.z * v.z + v.w * v.w;
  }
  cnorm[r] = s;
}

// cbT[q][k][c] = cb[q][c][k]  (coalesced writes; reads absorbed by L2/L3)
__global__ void k_transpose(const float* __restrict__ cb, float* __restrict__ cbT) {
  unsigned t = blockIdx.x * blockDim.x + threadIdx.x;  // 0..4194303
  unsigned c = t & (CODES - 1);
  unsigned k = (t >> 10) & (DIM - 1);
  unsigned q = t >> 19;
  cbT[t] = cb[(((size_t)q << 10) | c) * DIM + k];
}

__device__ __forceinline__ float getc(const float4& v, int k) {
  return k == 0 ? v.x : k == 1 ? v.y : k == 2 ? v.z : v.w;
}

// Stage one k-chunk (KC x 1024 floats = 16KB) into LDS, layout [k][c].
// useT: coalesced global_load_lds from transposed codebook (dest = uniform
// wave base + lane*16B, matching lane-consecutive float4 slots).
__device__ __forceinline__ void stage_chunk(const float* __restrict__ src, float* st,
                                            int q, int kc, int tid, int pg, int useT)
{
  if (useT) {
    const float* g = src + ((size_t)q * DIM + (size_t)kc * KC) * CODES + (tid << 2);
    float* l = st + (pg << 8);   // wave-uniform base (floats); HW adds lane*16B
    #pragma unroll
    for (int i = 0; i < KC; ++i) {
      __builtin_amdgcn_global_load_lds(
          (const __attribute__((address_space(1))) void*)(g + i * CODES),
          (__attribute__((address_space(3))) void*)(l + i * CODES), 16, 0, 0);
    }
  } else {
    // fallback: stage[i][c] = cb[q][c][kc*KC+i]; thread handles 4 codes
    #pragma unroll
    for (int cc = 0; cc < 4; ++cc) {
      const int c = (tid << 2) + cc;
      const float4 v = *(const float4*)(src + ((size_t)q * CODES + c) * DIM + kc * KC);
      st[0 * CODES + c] = v.x;
      st[1 * CODES + c] = v.y;
      st[2 * CODES + c] = v.z;
      st[3 * CODES + c] = v.w;
    }
  }
}

__launch_bounds__(NTHR, 2)
__global__ void k_main(const float* __restrict__ x, const float* __restrict__ cb,
                       const float* __restrict__ cbSrc,   // cbT if useT else cb
                       const float* __restrict__ cnorm,
                       double* __restrict__ lossAcc,
                       float* __restrict__ out, int useT)
{
  __shared__ __align__(16) float resid[MPTS][DIM];      // 32 KB fp32 residual
  __shared__ __align__(16) float stage[2][KC][CODES];   // 32 KB double-buffered codes
  __shared__ int idxs[MPTS][NUMQ];                      // chosen code per (pt,q)
  __shared__ float s1h[MPTS][2];                        // per-half top-1 score
  __shared__ int   cnd[MPTS][2][5];                     // per-half candidates
  __shared__ int   ccnt[MPTS][2];
  __shared__ double lred[4];

  const int tid = threadIdx.x;
  const int wg  = blockIdx.x;
  const int cl  = tid & 63;        // lane in wave
  const int pg  = tid >> 6;        // wave id
  const int ph  = pg >> 1;         // point-half: pts ph*8 .. +8
  const int chh = pg & 1;          // code-half: codes chh*512 .. +512

  // ---- init residual = x (coalesced float4)
  for (int t = tid; t < MPTS * DIM / 4; t += NTHR) {
    int p = t >> 7, d4 = t & 127;
    float4 v = *(const float4*)(x + ((size_t)(wg * MPTS + p)) * DIM + d4 * 4);
    *(float4*)&resid[p][d4 * 4] = v;
  }
  __syncthreads();

  for (int q = 0; q < NUMQ; ++q) {
    // acc[ii][g]: point ph*8+ii, code chh*512 + g*256 + cl*4 + comp
    float4 acc[8][2];
    #pragma unroll
    for (int ii = 0; ii < 8; ++ii) {
      acc[ii][0] = make_float4(0.f, 0.f, 0.f, 0.f);
      acc[ii][1] = make_float4(0.f, 0.f, 0.f, 0.f);
    }

    stage_chunk(cbSrc, &stage[0][0][0], q, 0, tid, pg, useT);
    __syncthreads();

    #pragma unroll 1
    for (int kc = 0; kc < NKC; ++kc) {
      if (kc + 1 < NKC)
        stage_chunk(cbSrc, &stage[(kc + 1) & 1][0][0], q, kc + 1, tid, pg, useT);
      const float* st = &stage[kc & 1][0][0];
      float4 rv[8];
      #pragma unroll
      for (int ii = 0; ii < 8; ++ii)
        rv[ii] = *(const float4*)&resid[(ph << 3) + ii][kc << 2];  // broadcast
      #pragma unroll
      for (int kk = 0; kk < 4; ++kk) {
        float4 cv[2];
        #pragma unroll
        for (int g = 0; g < 2; ++g)
          cv[g] = *(const float4*)&st[kk * CODES + (chh << 9) + (g << 8) + (cl << 2)];
        #pragma unroll
        for (int ii = 0; ii < 8; ++ii) {
          const float r = getc(rv[ii], kk);
          #pragma unroll
          for (int g = 0; g < 2; ++g) {
            acc[ii][g].x = fmaf(r, cv[g].x, acc[ii][g].x);
            acc[ii][g].y = fmaf(r, cv[g].y, acc[ii][g].y);
            acc[ii][g].z = fmaf(r, cv[g].z, acc[ii][g].z);
            acc[ii][g].w = fmaf(r, cv[g].w, acc[ii][g].w);
          }
        }
      }
      __syncthreads();
    }

    // ---- scores = -2*dot + ||c||^2 (fp32, approximate; eps covers error)
    {
      const float* cnq = cnorm + q * CODES + (chh << 9);
      float4 cn[2];
      #pragma unroll
      for (int g = 0; g < 2; ++g) cn[g] = *(const float4*)&cnq[(g << 8) + (cl << 2)];
      #pragma unroll
      for (int ii = 0; ii < 8; ++ii)
        #pragma unroll
        for (int g = 0; g < 2; ++g) {
          acc[ii][g].x = -2.0f * acc[ii][g].x + cn[g].x;
          acc[ii][g].y = -2.0f * acc[ii][g].y + cn[g].y;
          acc[ii][g].z = -2.0f * acc[ii][g].z + cn[g].z;
          acc[ii][g].w = -2.0f * acc[ii][g].w + cn[g].w;
        }
    }

    const int idbase = (chh << 9) + (cl << 2);  // global code id of acc[.][0].x

    // ---- per-half top-1 per point
    #pragma unroll
    for (int ii = 0; ii < 8; ++ii) {
      float s1 = acc[ii][0].x; int i1 = idbase;
      auto upd = [&](float s, int id) { if (s < s1) { s1 = s; i1 = id; } };
      upd(acc[ii][0].y, idbase + 1); upd(acc[ii][0].z, idbase + 2); upd(acc[ii][0].w, idbase + 3);
      upd(acc[ii][1].x, idbase + 256); upd(acc[ii][1].y, idbase + 257);
      upd(acc[ii][1].z, idbase + 258); upd(acc[ii][1].w, idbase + 259);
      #pragma unroll
      for (int m = 1; m < 64; m <<= 1) {
        float os = __shfl_xor(s1, m); int oid = __shfl_xor(i1, m);
        if (os < s1 || (os == s1 && oid < i1)) { s1 = os; i1 = oid; }
      }
      if (cl == 0) s1h[(ph << 3) + ii][chh] = s1;
    }
    __syncthreads();

    // ---- per-half candidate collection within margin of GLOBAL fp32 min
    #pragma unroll 1
    for (int ii = 0; ii < 8; ++ii) {
      const int p = (ph << 3) + ii;
      const float gm = fminf(s1h[p][0], s1h[p][1]);
      const float lim = gm + 0.25f + 5e-5f * fabsf(gm);
      int c0 = -1, c1 = -1, c2 = -1, c3 = -1, c4 = -1; int nc = 0;
      #pragma unroll 1
      for (int r = 0; r < 5; ++r) {
        float sb = 3.0e38f; int ib = 0x7FFFFFFF;
        auto cons = [&](float s, int id) {
          if (s <= lim && id != c0 && id != c1 && id != c2 && id != c3 && id != c4) {
            if (s < sb || (s == sb && id < ib)) { sb = s; ib = id; }
          }
        };
        cons(acc[ii][0].x, idbase); cons(acc[ii][0].y, idbase + 1);
        cons(acc[ii][0].z, idbase + 2); cons(acc[ii][0].w, idbase + 3);
        cons(acc[ii][1].x, idbase + 256); cons(acc[ii][1].y, idbase + 257);
        cons(acc[ii][1].z, idbase + 258); cons(acc[ii][1].w, idbase + 259);
        #pragma unroll
        for (int m = 1; m < 64; m <<= 1) {
          float os = __shfl_xor(sb, m); int oid = __shfl_xor(ib, m);
          if (os < sb || (os == sb && oid < ib)) { sb = os; ib = oid; }
        }
        if (ib == 0x7FFFFFFF) break;
        if (r == 0) c0 = ib; else if (r == 1) c1 = ib; else if (r == 2) c2 = ib;
        else if (r == 3) c3 = ib; else c4 = ib;
        ++nc;
      }
      if (cl == 0) {
        ccnt[p][chh] = nc;
        cnd[p][chh][0] = c0; cnd[p][chh][1] = c1; cnd[p][chh][2] = c2;
        cnd[p][chh][3] = c3; cnd[p][chh][4] = c4;
      }
    }
    __syncthreads();

    // ---- merge halves + exact fp64 refinement (chh==0 waves, wave-coop)
    if (chh == 0) {
      #pragma unroll 1
      for (int ii = 0; ii < 8; ++ii) {
        const int p = (ph << 3) + ii;
        const int n0 = ccnt[p][0], n1 = ccnt[p][1];
        const int tot = n0 + n1;
        int winner;
        if (tot == 1) {
          winner = n0 ? cnd[p][0][0] : cnd[p][1][0];
        } else {
          int cand[10];
          for (int j = 0; j < n0; ++j) cand[j] = cnd[p][0][j];
          for (int j = 0; j < n1; ++j) cand[n0 + j] = cnd[p][1][j];
          // exact fp64: rebuild residual chain ((x-c0)-c1)-... bit-exactly
          const size_t gp = (size_t)wg * MPTS + p;
          double rh[8];
          const float* xr = x + gp * DIM + (cl << 3);
          #pragma unroll
          for (int j = 0; j < 8; ++j) rh[j] = (double)xr[j];
          #pragma unroll 1
          for (int t = 0; t < q; ++t) {
            const float* cr = cb + ((size_t)t * CODES + idxs[p][t]) * DIM + (cl << 3);
            #pragma unroll
            for (int j = 0; j < 8; ++j) rh[j] -= (double)cr[j];
          }
          double bs = 1.0e300; int bi = 0x7FFFFFFF;
          #pragma unroll 1
          for (int t = 0; t < tot; ++t) {
            const int cc = cand[t];
            const float* cr = cb + ((size_t)q * CODES + cc) * DIM + (cl << 3);
            double dt = 0.0, cs = 0.0;
            #pragma unroll
            for (int j = 0; j < 8; ++j) {
              double cd = (double)cr[j];
              dt += rh[j] * cd; cs += cd * cd;
            }
            #pragma unroll
            for (int m = 1; m < 64; m <<= 1) { dt += __shfl_xor(dt, m); cs += __shfl_xor(cs, m); }
            double s = -2.0 * dt + cs;
            if (s < bs || (s == bs && cc < bi)) { bs = s; bi = cc; }
          }
          winner = bi;
        }
        if (cl == 0) idxs[p][q] = winner;
      }
    }
    __syncthreads();

    // ---- residual update + commit-loss partial (16 threads per point)
    {
      const int p = tid >> 4;
      const int l16 = tid & 15;
      const int w = idxs[p][q];
      const float4* cr = (const float4*)(cb + ((size_t)q * CODES + w) * DIM);
      float4* rr = (float4*)&resid[p][0];
      double ls = 0.0;
      #pragma unroll
      for (int t = 0; t < 8; ++t) {
        const int col4 = t * 16 + l16;
        float4 qv = cr[col4], rv = rr[col4];
        float dx = qv.x - rv.x, dy = qv.y - rv.y, dz = qv.z - rv.z, dw = qv.w - rv.w;
        ls += (double)dx * dx + (double)dy * dy + (double)dz * dz + (double)dw * dw;
        rv.x -= qv.x; rv.y -= qv.y; rv.z -= qv.z; rv.w -= qv.w;
        rr[col4] = rv;
      }
      #pragma unroll
      for (int m = 1; m < 64; m <<= 1) ls += __shfl_xor(ls, m);
      if (cl == 0) lred[pg] = ls;
      __syncthreads();
      if (tid == 0) atomicAdd(lossAcc + q, lred[0] + lred[1] + lred[2] + lred[3]);
      __syncthreads();
    }
  } // q

  // ---- outputs: quantized = x - residual_final; indices as float
  for (int t = tid; t < MPTS * DIM / 4; t += NTHR) {
    int p = t >> 7, d4 = t & 127;
    size_t off = ((size_t)(wg * MPTS + p)) * DIM + d4 * 4;
    float4 xv = *(const float4*)(x + off);
    float4 rv = *(const float4*)&resid[p][d4 * 4];
    float4 o;
    o.x = xv.x - rv.x; o.y = xv.y - rv.y; o.z = xv.z - rv.z; o.w = xv.w - rv.w;
    *(float4*)(out + off) = o;
  }
  if (tid < MPTS) {
    const size_t gp = (size_t)wg * MPTS + tid;
    float* ob = out + OUT_IDX + gp * NUMQ;
    #pragma unroll
    for (int j = 0; j < NUMQ; ++j) ob[j] = (float)idxs[tid][j];
  }
}

__global__ void k_fin(const double* __restrict__ loss, float* __restrict__ out) {
  int t = threadIdx.x;
  if (t < NUMQ)
    out[OUT_LOSS + t] = (float)(loss[t] / (double)((size_t)BATCH * SEQ * DIM));
}

extern "C" void kernel_launch(void* const* d_in, const int* in_sizes, int n_in,
                              void* d_out, int out_size, void* d_ws, size_t ws_size,
                              hipStream_t stream) {
  (void)in_sizes; (void)n_in; (void)out_size;
  const float* x  = (const float*)d_in[0];
  const float* cb = (const float*)d_in[1];
  float* out = (float*)d_out;
  char* ws = (char*)d_ws;
  double* loss = (double*)(ws + WS_LOSS);
  float* cnorm = (float*)(ws + WS_CNORM);
  float* cbT   = (float*)(ws + WS_CBT);
  const int useT = (ws_size >= WS_NEED_T) ? 1 : 0;

  k_zero<<<1, 64, 0, stream>>>(loss);
  k_cnorm<<<NUMQ * CODES / NTHR, NTHR, 0, stream>>>(cb, cnorm);
  if (useT)
    k_transpose<<<NUMQ * CODES * DIM / NTHR, NTHR, 0, stream>>>(cb, cbT);
  k_main<<<NWG, NTHR, 0, stream>>>(x, cb, useT ? cbT : cb, cnorm, loss, out, useT);
  k_fin<<<1, 64, 0, stream>>>(loss, out);
}

// Round 3
// 2194.145 us; speedup vs baseline: 7.9541x; 7.9541x over previous
//
#include <hip/hip_runtime.h>
#include <cstdint>
#include <cstddef>

// ---------------------------------------------------------------------------
// Residual VQ (SoundStream Alg.1) on MI355X — R3.
// R2 post-mortem: candidate-collection loop had "#pragma unroll 1" with
// acc[ii] runtime-indexed -> whole accumulator spilled to scratch -> 51 GB
// HBM writes, VALUBusy 6.8%. R3 = R2 with that loop fully unrolled (constant
// index, acc stays in VGPRs). Structure: 16 pts/WG, ~67KB LDS -> 2 blocks/CU;
// waves split codes 2-way x points 2-way; fp32 distance GEMM + exact fp64
// refinement of near-ties (emitted indices = exact-arithmetic argmin).
// ---------------------------------------------------------------------------

#define BATCH 8
#define SEQ   2048
#define DIM   512
#define NUMQ  8
#define CODES 1024
#define NPTS  (BATCH*SEQ)            // 16384
#define MPTS  16                     // points per workgroup
#define NWG   (NPTS/MPTS)            // 1024
#define NTHR  256
#define KC    4                      // k-chunk depth staged per buffer
#define NKC   (DIM/KC)               // 128

#define OUT_IDX   (BATCH*SEQ*DIM)             // 8388608
#define OUT_LOSS  (OUT_IDX + BATCH*SEQ*NUMQ)  // 8519680

#define WS_LOSS    0                          // 8 doubles
#define WS_CNORM   1024                       // 8192 floats
#define WS_CBT     40960                      // 8*512*1024 floats (k-major)
#define WS_NEED_T  (WS_CBT + (size_t)NUMQ*DIM*CODES*4)

__global__ void k_zero(double* loss) {
  if (threadIdx.x < NUMQ) loss[threadIdx.x] = 0.0;
}

// per-code squared norm (fp32; only feeds the approximate fp32 scores)
__global__ void k_cnorm(const float* __restrict__ cb, float* __restrict__ cnorm) {
  int r = blockIdx.x * blockDim.x + threadIdx.x;      // 0..8191
  const float* row = cb + (size_t)r * DIM;
  float s = 0.f;
  for (int d = 0; d < DIM; d += 4) {
    float4 v = *(const float4*)(row + d);
    s += v.x * v.x + v.y * v.y + v.z * v.z + v.w * v.w;
  }
  cnorm[r] = s;
}

// cbT[q][k][c] = cb[q][c][k]  (coalesced writes; reads absorbed by L2/L3)
__global__ void k_transpose(const float* __restrict__ cb, float* __restrict__ cbT) {
  unsigned t = blockIdx.x * blockDim.x + threadIdx.x;  // 0..4194303
  unsigned c = t & (CODES - 1);
  unsigned k = (t >> 10) & (DIM - 1);
  unsigned q = t >> 19;
  cbT[t] = cb[(((size_t)q << 10) | c) * DIM + k];
}

__device__ __forceinline__ float getc(const float4& v, int k) {
  return k == 0 ? v.x : k == 1 ? v.y : k == 2 ? v.z : v.w;
}

// Stage one k-chunk (KC x 1024 floats = 16KB) into LDS, layout [k][c].
// useT: coalesced global_load_lds from transposed codebook (dest = uniform
// wave base + lane*16B, matching lane-consecutive float4 slots).
__device__ __forceinline__ void stage_chunk(const float* __restrict__ src, float* st,
                                            int q, int kc, int tid, int pg, int useT)
{
  if (useT) {
    const float* g = src + ((size_t)q * DIM + (size_t)kc * KC) * CODES + (tid << 2);
    float* l = st + (pg << 8);   // wave-uniform base (floats); HW adds lane*16B
    #pragma unroll
    for (int i = 0; i < KC; ++i) {
      __builtin_amdgcn_global_load_lds(
          (const __attribute__((address_space(1))) void*)(g + i * CODES),
          (__attribute__((address_space(3))) void*)(l + i * CODES), 16, 0, 0);
    }
  } else {
    // fallback: stage[i][c] = cb[q][c][kc*KC+i]; thread handles 4 codes
    #pragma unroll
    for (int cc = 0; cc < 4; ++cc) {
      const int c = (tid << 2) + cc;
      const float4 v = *(const float4*)(src + ((size_t)q * CODES + c) * DIM + kc * KC);
      st[0 * CODES + c] = v.x;
      st[1 * CODES + c] = v.y;
      st[2 * CODES + c] = v.z;
      st[3 * CODES + c] = v.w;
    }
  }
}

__launch_bounds__(NTHR, 2)
__global__ void k_main(const float* __restrict__ x, const float* __restrict__ cb,
                       const float* __restrict__ cbSrc,   // cbT if useT else cb
                       const float* __restrict__ cnorm,
                       double* __restrict__ lossAcc,
                       float* __restrict__ out, int useT)
{
  __shared__ __align__(16) float resid[MPTS][DIM];      // 32 KB fp32 residual
  __shared__ __align__(16) float stage[2][KC][CODES];   // 32 KB double-buffered codes
  __shared__ int idxs[MPTS][NUMQ];                      // chosen code per (pt,q)
  __shared__ float s1h[MPTS][2];                        // per-half top-1 score
  __shared__ int   cnd[MPTS][2][5];                     // per-half candidates
  __shared__ int   ccnt[MPTS][2];
  __shared__ double lred[4];

  const int tid = threadIdx.x;
  const int wg  = blockIdx.x;
  const int cl  = tid & 63;        // lane in wave
  const int pg  = tid >> 6;        // wave id
  const int ph  = pg >> 1;         // point-half: pts ph*8 .. +8
  const int chh = pg & 1;          // code-half: codes chh*512 .. +512

  // ---- init residual = x (coalesced float4)
  for (int t = tid; t < MPTS * DIM / 4; t += NTHR) {
    int p = t >> 7, d4 = t & 127;
    float4 v = *(const float4*)(x + ((size_t)(wg * MPTS + p)) * DIM + d4 * 4);
    *(float4*)&resid[p][d4 * 4] = v;
  }
  __syncthreads();

  for (int q = 0; q < NUMQ; ++q) {
    // acc[ii][g]: point ph*8+ii, code chh*512 + g*256 + cl*4 + comp
    float4 acc[8][2];
    #pragma unroll
    for (int ii = 0; ii < 8; ++ii) {
      acc[ii][0] = make_float4(0.f, 0.f, 0.f, 0.f);
      acc[ii][1] = make_float4(0.f, 0.f, 0.f, 0.f);
    }

    stage_chunk(cbSrc, &stage[0][0][0], q, 0, tid, pg, useT);
    __syncthreads();

    #pragma unroll 1
    for (int kc = 0; kc < NKC; ++kc) {
      if (kc + 1 < NKC)
        stage_chunk(cbSrc, &stage[(kc + 1) & 1][0][0], q, kc + 1, tid, pg, useT);
      const float* st = &stage[kc & 1][0][0];
      float4 rv[8];
      #pragma unroll
      for (int ii = 0; ii < 8; ++ii)
        rv[ii] = *(const float4*)&resid[(ph << 3) + ii][kc << 2];  // broadcast
      #pragma unroll
      for (int kk = 0; kk < 4; ++kk) {
        float4 cv[2];
        #pragma unroll
        for (int g = 0; g < 2; ++g)
          cv[g] = *(const float4*)&st[kk * CODES + (chh << 9) + (g << 8) + (cl << 2)];
        #pragma unroll
        for (int ii = 0; ii < 8; ++ii) {
          const float r = getc(rv[ii], kk);
          #pragma unroll
          for (int g = 0; g < 2; ++g) {
            acc[ii][g].x = fmaf(r, cv[g].x, acc[ii][g].x);
            acc[ii][g].y = fmaf(r, cv[g].y, acc[ii][g].y);
            acc[ii][g].z = fmaf(r, cv[g].z, acc[ii][g].z);
            acc[ii][g].w = fmaf(r, cv[g].w, acc[ii][g].w);
          }
        }
      }
      __syncthreads();
    }

    // ---- scores = -2*dot + ||c||^2 (fp32, approximate; eps covers error)
    {
      const float* cnq = cnorm + q * CODES + (chh << 9);
      float4 cn[2];
      #pragma unroll
      for (int g = 0; g < 2; ++g) cn[g] = *(const float4*)&cnq[(g << 8) + (cl << 2)];
      #pragma unroll
      for (int ii = 0; ii < 8; ++ii)
        #pragma unroll
        for (int g = 0; g < 2; ++g) {
          acc[ii][g].x = -2.0f * acc[ii][g].x + cn[g].x;
          acc[ii][g].y = -2.0f * acc[ii][g].y + cn[g].y;
          acc[ii][g].z = -2.0f * acc[ii][g].z + cn[g].z;
          acc[ii][g].w = -2.0f * acc[ii][g].w + cn[g].w;
        }
    }

    const int idbase = (chh << 9) + (cl << 2);  // global code id of acc[.][0].x

    // ---- per-half top-1 per point
    #pragma unroll
    for (int ii = 0; ii < 8; ++ii) {
      float s1 = acc[ii][0].x; int i1 = idbase;
      auto upd = [&](float s, int id) { if (s < s1) { s1 = s; i1 = id; } };
      upd(acc[ii][0].y, idbase + 1); upd(acc[ii][0].z, idbase + 2); upd(acc[ii][0].w, idbase + 3);
      upd(acc[ii][1].x, idbase + 256); upd(acc[ii][1].y, idbase + 257);
      upd(acc[ii][1].z, idbase + 258); upd(acc[ii][1].w, idbase + 259);
      #pragma unroll
      for (int m = 1; m < 64; m <<= 1) {
        float os = __shfl_xor(s1, m); int oid = __shfl_xor(i1, m);
        if (os < s1 || (os == s1 && oid < i1)) { s1 = os; i1 = oid; }
      }
      if (cl == 0) s1h[(ph << 3) + ii][chh] = s1;
    }
    __syncthreads();

    // ---- per-half candidate collection within margin of GLOBAL fp32 min
    //      FULL unroll over ii: acc[ii] must be constant-indexed (R2 lesson:
    //      "#pragma unroll 1" here spilled acc to scratch -> 51 GB writes)
    #pragma unroll
    for (int ii = 0; ii < 8; ++ii) {
      const int p = (ph << 3) + ii;
      const float gm = fminf(s1h[p][0], s1h[p][1]);
      const float lim = gm + 0.25f + 5e-5f * fabsf(gm);
      int c0 = -1, c1 = -1, c2 = -1, c3 = -1, c4 = -1; int nc = 0;
      #pragma unroll 1
      for (int r = 0; r < 5; ++r) {
        float sb = 3.0e38f; int ib = 0x7FFFFFFF;
        auto cons = [&](float s, int id) {
          if (s <= lim && id != c0 && id != c1 && id != c2 && id != c3 && id != c4) {
            if (s < sb || (s == sb && id < ib)) { sb = s; ib = id; }
          }
        };
        cons(acc[ii][0].x, idbase); cons(acc[ii][0].y, idbase + 1);
        cons(acc[ii][0].z, idbase + 2); cons(acc[ii][0].w, idbase + 3);
        cons(acc[ii][1].x, idbase + 256); cons(acc[ii][1].y, idbase + 257);
        cons(acc[ii][1].z, idbase + 258); cons(acc[ii][1].w, idbase + 259);
        #pragma unroll
        for (int m = 1; m < 64; m <<= 1) {
          float os = __shfl_xor(sb, m); int oid = __shfl_xor(ib, m);
          if (os < sb || (os == sb && oid < ib)) { sb = os; ib = oid; }
        }
        if (ib == 0x7FFFFFFF) break;
        if (r == 0) c0 = ib; else if (r == 1) c1 = ib; else if (r == 2) c2 = ib;
        else if (r == 3) c3 = ib; else c4 = ib;
        ++nc;
      }
      if (cl == 0) {
        ccnt[p][chh] = nc;
        cnd[p][chh][0] = c0; cnd[p][chh][1] = c1; cnd[p][chh][2] = c2;
        cnd[p][chh][3] = c3; cnd[p][chh][4] = c4;
      }
    }
    __syncthreads();

    // ---- merge halves + exact fp64 refinement (chh==0 waves, wave-coop).
    //      Reads only LDS arrays (no acc) -> unroll 1 is safe here.
    if (chh == 0) {
      #pragma unroll 1
      for (int ii = 0; ii < 8; ++ii) {
        const int p = (ph << 3) + ii;
        const int n0 = ccnt[p][0], n1 = ccnt[p][1];
        const int tot = n0 + n1;
        int winner;
        if (tot == 1) {
          winner = n0 ? cnd[p][0][0] : cnd[p][1][0];
        } else {
          // exact fp64: rebuild residual chain ((x-c0)-c1)-... bit-exactly
          const size_t gp = (size_t)wg * MPTS + p;
          double rh[8];
          const float* xr = x + gp * DIM + (cl << 3);
          #pragma unroll
          for (int j = 0; j < 8; ++j) rh[j] = (double)xr[j];
          #pragma unroll 1
          for (int t = 0; t < q; ++t) {
            const float* cr = cb + ((size_t)t * CODES + idxs[p][t]) * DIM + (cl << 3);
            #pragma unroll
            for (int j = 0; j < 8; ++j) rh[j] -= (double)cr[j];
          }
          double bs = 1.0e300; int bi = 0x7FFFFFFF;
          #pragma unroll 1
          for (int t = 0; t < tot; ++t) {
            const int cc = (t < n0) ? cnd[p][0][t] : cnd[p][1][t - n0];
            const float* cr = cb + ((size_t)q * CODES + cc) * DIM + (cl << 3);
            double dt = 0.0, cs = 0.0;
            #pragma unroll
            for (int j = 0; j < 8; ++j) {
              double cd = (double)cr[j];
              dt += rh[j] * cd; cs += cd * cd;
            }
            #pragma unroll
            for (int m = 1; m < 64; m <<= 1) { dt += __shfl_xor(dt, m); cs += __shfl_xor(cs, m); }
            double s = -2.0 * dt + cs;
            if (s < bs || (s == bs && cc < bi)) { bs = s; bi = cc; }
          }
          winner = bi;
        }
        if (cl == 0) idxs[p][q] = winner;
      }
    }
    __syncthreads();

    // ---- residual update + commit-loss partial (16 threads per point)
    {
      const int p = tid >> 4;
      const int l16 = tid & 15;
      const int w = idxs[p][q];
      const float4* cr = (const float4*)(cb + ((size_t)q * CODES + w) * DIM);
      float4* rr = (float4*)&resid[p][0];
      double ls = 0.0;
      #pragma unroll
      for (int t = 0; t < 8; ++t) {
        const int col4 = t * 16 + l16;
        float4 qv = cr[col4], rv = rr[col4];
        float dx = qv.x - rv.x, dy = qv.y - rv.y, dz = qv.z - rv.z, dw = qv.w - rv.w;
        ls += (double)dx * dx + (double)dy * dy + (double)dz * dz + (double)dw * dw;
        rv.x -= qv.x; rv.y -= qv.y; rv.z -= qv.z; rv.w -= qv.w;
        rr[col4] = rv;
      }
      #pragma unroll
      for (int m = 1; m < 64; m <<= 1) ls += __shfl_xor(ls, m);
      if (cl == 0) lred[pg] = ls;
      __syncthreads();
      if (tid == 0) atomicAdd(lossAcc + q, lred[0] + lred[1] + lred[2] + lred[3]);
      __syncthreads();
    }
  } // q

  // ---- outputs: quantized = x - residual_final; indices as float
  for (int t = tid; t < MPTS * DIM / 4; t += NTHR) {
    int p = t >> 7, d4 = t & 127;
    size_t off = ((size_t)(wg * MPTS + p)) * DIM + d4 * 4;
    float4 xv = *(const float4*)(x + off);
    float4 rv = *(const float4*)&resid[p][d4 * 4];
    float4 o;
    o.x = xv.x - rv.x; o.y = xv.y - rv.y; o.z = xv.z - rv.z; o.w = xv.w - rv.w;
    *(float4*)(out + off) = o;
  }
  if (tid < MPTS) {
    const size_t gp = (size_t)wg * MPTS + tid;
    float* ob = out + OUT_IDX + gp * NUMQ;
    #pragma unroll
    for (int j = 0; j < NUMQ; ++j) ob[j] = (float)idxs[tid][j];
  }
}

__global__ void k_fin(const double* __restrict__ loss, float* __restrict__ out) {
  int t = threadIdx.x;
  if (t < NUMQ)
    out[OUT_LOSS + t] = (float)(loss[t] / (double)((size_t)BATCH * SEQ * DIM));
}

extern "C" void kernel_launch(void* const* d_in, const int* in_sizes, int n_in,
                              void* d_out, int out_size, void* d_ws, size_t ws_size,
                              hipStream_t stream) {
  (void)in_sizes; (void)n_in; (void)out_size;
  const float* x  = (const float*)d_in[0];
  const float* cb = (const float*)d_in[1];
  float* out = (float*)d_out;
  char* ws = (char*)d_ws;
  double* loss = (double*)(ws + WS_LOSS);
  float* cnorm = (float*)(ws + WS_CNORM);
  float* cbT   = (float*)(ws + WS_CBT);
  const int useT = (ws_size >= WS_NEED_T) ? 1 : 0;

  k_zero<<<1, 64, 0, stream>>>(loss);
  k_cnorm<<<NUMQ * CODES / NTHR, NTHR, 0, stream>>>(cb, cnorm);
  if (useT)
    k_transpose<<<NUMQ * CODES * DIM / NTHR, NTHR, 0, stream>>>(cb, cbT);
  k_main<<<NWG, NTHR, 0, stream>>>(x, cb, useT ? cbT : cb, cnorm, loss, out, useT);
  k_fin<<<1, 64, 0, stream>>>(loss, out);
}